// Round 4
// baseline (83.692 us; speedup 1.0000x reference)
//
#include <hip/hip_runtime.h>
#include <math.h>

#define KPTS 133
#define SPW 4     // samples per wave (16 lanes each)
#define WPB 4     // waves per block (256 threads)
#define PPL 9     // max points per lane (ceil(133/16))

__device__ __forceinline__ float det3(float a0, float a1, float a2,
                                      float b0, float b1, float b2,
                                      float c0, float c1, float c2) {
    return a0 * (b1 * c2 - b2 * c1)
         - a1 * (b0 * c2 - b2 * c0)
         + a2 * (b0 * c1 - b1 * c0);
}

// Barrier-free structure: 16 lanes per sample, 4 samples per wave.
// 1) Each lane loads 8-9 points (stride-16) of target+output into registers,
//    accumulates 16 raw moments.
// 2) 4-stage value-splitting butterfly within each 16-lane group -> lane l16
//    holds group-summed moment l16; 16 bpermute-gathers broadcast all 16
//    moments to every lane of the group.
// 3) ALL lanes redundantly solve their group's Horn quaternion eigenproblem
//    (same wave-issue cost as 4 masked lanes, zero divergence, no shfl-back).
// 4) Residual norms from register-held points; 6-shuffle wave reduce; one
//    partial per wave -> deterministic fixed-order reduce kernel.
// No __syncthreads, no LDS in the main kernel: every wave fully independent.
__global__ __launch_bounds__(256, 5) void pa_mpjpe_kernel(
    const float* __restrict__ outp,   // (N,K,3) output
    const float* __restrict__ tgtp,   // (N,K,3) target
    float* __restrict__ wave_sums,
    int nsamp)
{
    const int lane = threadIdx.x & 63;
    const int wid  = threadIdx.x >> 6;
    const int gw   = blockIdx.x * WPB + wid;   // global wave id
    const int l16  = lane & 15;                // lane within sample group
    const int s    = gw * SPW + (lane >> 4);   // this lane's sample
    const bool valid = (s < nsamp);

    const size_t sb = (size_t)(valid ? s : 0) * (KPTS * 3);
    const float* tb = tgtp + sb;
    const float* ob = outp + sb;

    // ---- load points + raw moments ----
    // red: [0..2]=sum_t, [3..5]=sum_o, [6..14]=sum t_a*o_b (row-major), [15]=sum t.t
    float tp[PPL][3], op[PPL][3];
    float red[16];
    #pragma unroll
    for (int i = 0; i < 16; ++i) red[i] = 0.0f;

    #pragma unroll
    for (int m = 0; m < PPL; ++m) {
        const int p = l16 + 16 * m;
        float t0 = 0.f, t1 = 0.f, t2 = 0.f, o0 = 0.f, o1 = 0.f, o2 = 0.f;
        if (p < KPTS) {
            t0 = tb[3 * p + 0]; t1 = tb[3 * p + 1]; t2 = tb[3 * p + 2];
            o0 = ob[3 * p + 0]; o1 = ob[3 * p + 1]; o2 = ob[3 * p + 2];
        }
        tp[m][0] = t0; tp[m][1] = t1; tp[m][2] = t2;
        op[m][0] = o0; op[m][1] = o1; op[m][2] = o2;
        red[0]  += t0;      red[1]  += t1;      red[2]  += t2;
        red[3]  += o0;      red[4]  += o1;      red[5]  += o2;
        red[6]  += t0 * o0; red[7]  += t0 * o1; red[8]  += t0 * o2;
        red[9]  += t1 * o0; red[10] += t1 * o1; red[11] += t1 * o2;
        red[12] += t2 * o0; red[13] += t2 * o1; red[14] += t2 * o2;
        red[15] += t0 * t0 + t1 * t1 + t2 * t2;
    }

    // ---- 4-stage value-splitting butterfly within 16-lane group ----
    // After 4 halving stages, lane l16 holds the group sum of red[l16].
    float v8[8];
    {
        const bool b = (lane & 1);
        #pragma unroll
        for (int m = 0; m < 8; ++m) {
            const float snd = b ? red[2 * m] : red[2 * m + 1];
            const float rcv = __shfl_xor(snd, 1, 64);
            v8[m] = (b ? red[2 * m + 1] : red[2 * m]) + rcv;
        }
    }
    float v4_[4];
    {
        const bool b = ((lane >> 1) & 1);
        #pragma unroll
        for (int m = 0; m < 4; ++m) {
            const float snd = b ? v8[2 * m] : v8[2 * m + 1];
            const float rcv = __shfl_xor(snd, 2, 64);
            v4_[m] = (b ? v8[2 * m + 1] : v8[2 * m]) + rcv;
        }
    }
    float v2_[2];
    {
        const bool b = ((lane >> 2) & 1);
        #pragma unroll
        for (int m = 0; m < 2; ++m) {
            const float snd = b ? v4_[2 * m] : v4_[2 * m + 1];
            const float rcv = __shfl_xor(snd, 4, 64);
            v2_[m] = (b ? v4_[2 * m + 1] : v4_[2 * m]) + rcv;
        }
    }
    float v1;
    {
        const bool b = ((lane >> 3) & 1);
        const float snd = b ? v2_[0] : v2_[1];
        const float rcv = __shfl_xor(snd, 8, 64);
        v1 = (b ? v2_[1] : v2_[0]) + rcv;
    }

    // gather all 16 group moments to every lane (redundant solve per group)
    const int gbase = lane & 48;
    float m_[16];
    #pragma unroll
    for (int j = 0; j < 16; ++j) m_[j] = __shfl(v1, gbase + j, 64);

    // ---- Horn quaternion eigenproblem (all lanes, uniform within group) ----
    const float invK = 1.0f / (float)KPTS;
    const float mu1x = m_[0] * invK, mu1y = m_[1] * invK, mu1z = m_[2] * invK;
    const float mu2x = m_[3] * invK, mu2y = m_[4] * invK, mu2z = m_[5] * invK;

    const float Sxx = m_[6]  - m_[0] * m_[3] * invK;
    const float Sxy = m_[7]  - m_[0] * m_[4] * invK;
    const float Sxz = m_[8]  - m_[0] * m_[5] * invK;
    const float Syx = m_[9]  - m_[1] * m_[3] * invK;
    const float Syy = m_[10] - m_[1] * m_[4] * invK;
    const float Syz = m_[11] - m_[1] * m_[5] * invK;
    const float Szx = m_[12] - m_[2] * m_[3] * invK;
    const float Szy = m_[13] - m_[2] * m_[4] * invK;
    const float Szz = m_[14] - m_[2] * m_[5] * invK;
    const float var1 = m_[15] - (m_[0] * m_[0] + m_[1] * m_[1] + m_[2] * m_[2]) * invK;

    const float N00 = Sxx + Syy + Szz;
    const float N01 = Syz - Szy, N02 = Szx - Sxz, N03 = Sxy - Syx;
    const float N11 = Sxx - Syy - Szz, N12 = Sxy + Syx, N13 = Szx + Sxz;
    const float N22 = -Sxx + Syy - Szz, N23 = Syz + Szy;
    const float N33 = -Sxx - Syy + Szz;

    const float trKtK = Sxx * Sxx + Sxy * Sxy + Sxz * Sxz
                      + Syx * Syx + Syy * Syy + Syz * Syz
                      + Szx * Szx + Szy * Szy + Szz * Szz;
    const float c2 = -2.0f * trKtK;
    const float detK = det3(Sxx, Sxy, Sxz, Syx, Syy, Syz, Szx, Szy, Szz);
    const float c1 = -8.0f * detK;
    const float c0 =
          N00 * det3(N11, N12, N13, N12, N22, N23, N13, N23, N33)
        - N01 * det3(N01, N12, N13, N02, N22, N23, N03, N23, N33)
        + N02 * det3(N01, N11, N13, N02, N12, N23, N03, N13, N33)
        - N03 * det3(N01, N11, N12, N02, N12, N22, N03, N13, N23);

    float lam = sqrtf(fmaxf(3.0f * trKtK, 0.0f));
    #pragma unroll
    for (int it = 0; it < 14; ++it) {
        const float l2 = lam * lam;
        const float P  = (l2 + c2) * l2 + c1 * lam + c0;
        const float Pp = (4.0f * l2 + 2.0f * c2) * lam + c1;
        lam -= P / Pp;
    }

    const float M00 = N00 - lam, M11 = N11 - lam, M22 = N22 - lam, M33 = N33 - lam;
    const float a0 =  det3(M11, N12, N13, N12, M22, N23, N13, N23, M33);
    const float a1 = -det3(N01, N12, N13, N02, M22, N23, N03, N23, M33);
    const float a2 =  det3(N01, M11, N13, N02, N12, N23, N03, N13, M33);
    const float a3 = -det3(N01, M11, N12, N02, N12, M22, N03, N13, N23);
    const float b0 = -det3(N01, N02, N03, N12, M22, N23, N13, N23, M33);
    const float b1 =  det3(M00, N02, N03, N02, M22, N23, N03, N23, M33);
    const float b2 = -det3(M00, N01, N03, N02, N12, N23, N03, N13, M33);
    const float b3 =  det3(M00, N01, N02, N02, N12, M22, N03, N13, N23);
    const float na = a0 * a0 + a1 * a1 + a2 * a2 + a3 * a3;
    const float nb = b0 * b0 + b1 * b1 + b2 * b2 + b3 * b3;
    float qw, qx, qy, qz;
    if (na >= nb) { qw = a0; qx = a1; qy = a2; qz = a3; }
    else          { qw = b0; qx = b1; qy = b2; qz = b3; }
    const float qn = rsqrtf(fmaxf(qw * qw + qx * qx + qy * qy + qz * qz, 1e-30f));
    qw *= qn; qx *= qn; qy *= qn; qz *= qn;

    const float R00 = 1.0f - 2.0f * (qy * qy + qz * qz);
    const float R01 = 2.0f * (qx * qy - qw * qz);
    const float R02 = 2.0f * (qx * qz + qw * qy);
    const float R10 = 2.0f * (qx * qy + qw * qz);
    const float R11 = 1.0f - 2.0f * (qx * qx + qz * qz);
    const float R12 = 2.0f * (qy * qz - qw * qx);
    const float R20 = 2.0f * (qx * qz - qw * qy);
    const float R21 = 2.0f * (qy * qz + qw * qx);
    const float R22 = 1.0f - 2.0f * (qx * qx + qy * qy);

    const float trRK = R00 * Sxx + R01 * Syx + R02 * Szx
                     + R10 * Sxy + R11 * Syy + R12 * Szy
                     + R20 * Sxz + R21 * Syz + R22 * Szz;
    const float scale = trRK / var1;

    const float sR00 = scale * R00, sR01 = scale * R01, sR02 = scale * R02;
    const float sR10 = scale * R10, sR11 = scale * R11, sR12 = scale * R12;
    const float sR20 = scale * R20, sR21 = scale * R21, sR22 = scale * R22;
    const float tx = mu2x - (sR00 * mu1x + sR01 * mu1y + sR02 * mu1z);
    const float ty = mu2y - (sR10 * mu1x + sR11 * mu1y + sR12 * mu1z);
    const float tz = mu2z - (sR20 * mu1x + sR21 * mu1y + sR22 * mu1z);

    // ---- residual norms from register-held points ----
    float rsum = 0.0f;
    #pragma unroll
    for (int m = 0; m < PPL; ++m) {
        const int p = l16 + 16 * m;
        if (valid && p < KPTS) {
            const float ax = sR00 * tp[m][0] + sR01 * tp[m][1] + sR02 * tp[m][2] + tx;
            const float ay = sR10 * tp[m][0] + sR11 * tp[m][1] + sR12 * tp[m][2] + ty;
            const float az = sR20 * tp[m][0] + sR21 * tp[m][1] + sR22 * tp[m][2] + tz;
            const float dx = op[m][0] - ax;
            const float dy = op[m][1] - ay;
            const float dz = op[m][2] - az;
            rsum += sqrtf(dx * dx + dy * dy + dz * dz);
        }
    }

    // group reduce (xor 1,2,4,8) then cross-group (xor 16,32): wave total
    rsum += __shfl_xor(rsum, 1, 64);
    rsum += __shfl_xor(rsum, 2, 64);
    rsum += __shfl_xor(rsum, 4, 64);
    rsum += __shfl_xor(rsum, 8, 64);
    rsum += __shfl_xor(rsum, 16, 64);
    rsum += __shfl_xor(rsum, 32, 64);

    if (lane == 0) wave_sums[gw] = rsum;
}

// Deterministic final reduction: one block, fixed summation order.
__global__ __launch_bounds__(256) void pa_reduce_kernel(
    const float* __restrict__ wave_sums, int n,
    float* __restrict__ out, float inv_total)
{
    __shared__ float sh[4];
    float v = 0.0f;
    for (int i = threadIdx.x; i < n; i += 256) v += wave_sums[i];
    #pragma unroll
    for (int off = 32; off >= 1; off >>= 1) v += __shfl_xor(v, off, 64);
    const int lane = threadIdx.x & 63;
    const int wid  = threadIdx.x >> 6;
    if (lane == 0) sh[wid] = v;
    __syncthreads();
    if (threadIdx.x == 0) out[0] = (sh[0] + sh[1] + sh[2] + sh[3]) * inv_total;
}

extern "C" void kernel_launch(void* const* d_in, const int* in_sizes, int n_in,
                              void* d_out, int out_size, void* d_ws, size_t ws_size,
                              hipStream_t stream) {
    const float* outp = (const float*)d_in[0];   // "output"
    const float* tgtp = (const float*)d_in[1];   // "target"
    const int nsamp   = in_sizes[0] / (KPTS * 3);
    const int nwaves  = (nsamp + SPW - 1) / SPW;
    const int nblocks = (nwaves + WPB - 1) / WPB;

    float* wsums = (float*)d_ws;

    pa_mpjpe_kernel<<<nblocks, 256, 0, stream>>>(outp, tgtp, wsums, nsamp);
    pa_reduce_kernel<<<1, 256, 0, stream>>>(
        wsums, nwaves, (float*)d_out,
        1.0f / ((float)nsamp * (float)KPTS));
}